// Round 16
// baseline (133.852 us; speedup 1.0000x reference)
//
#include <hip/hip_runtime.h>
#include <hip/hip_bf16.h>

// Problem constants
#define NT      32      // time steps
#define FEAT    128     // in/out features per step
#define TRIB    8       // band width in blocks
#define BATCH   8192
#define INSIZE  (NT*FEAT)   // 4096
#define OUTCOLS (NT*FEAT)   // 4096

typedef __bf16 bf16;
typedef __bf16 bf16x4 __attribute__((ext_vector_type(4)));
typedef __bf16 bf16x8 __attribute__((ext_vector_type(8)));
typedef float  f32x4  __attribute__((ext_vector_type(4)));

__host__ __device__ __forceinline__ int nb_of(int i){ return i < TRIB ? i + 1 : TRIB; }
__host__ __device__ __forceinline__ int lo_of(int i){ int l = i - TRIB + 1; return l > 0 ? l : 0; }
__host__ __device__ __forceinline__ long off_of(int i){
  long sum = (i <= TRIB) ? (long)i*(i+1)/2 : (long)(TRIB*(TRIB+1)/2) + (long)(i - TRIB)*TRIB;
  return sum * (long)(FEAT*FEAT);
}

// ---------------- conversion kernels ----------------
// cvt_x: 32 B loads + 16 B stores (R15-proven). R16: x reads are NON-TEMPORAL
// (f32 x is read once, never reused — keep it out of L3 so xb stays resident).

__global__ void cvt_x_kernel(const float* __restrict__ x, bf16* __restrict__ xb, long n8){
  long idx = (long)blockIdx.x * blockDim.x + threadIdx.x;
  long stride = (long)gridDim.x * blockDim.x;
  for (long i = idx; i < n8; i += stride){
    f32x4 v0 = __builtin_nontemporal_load((const f32x4*)(x + i*8));
    f32x4 v1 = __builtin_nontemporal_load((const f32x4*)(x + i*8 + 4));
    bf16x8 o;
    o[0]=(bf16)v0.x; o[1]=(bf16)v0.y; o[2]=(bf16)v0.z; o[3]=(bf16)v0.w;
    o[4]=(bf16)v1.x; o[5]=(bf16)v1.y; o[6]=(bf16)v1.z; o[7]=(bf16)v1.w;
    *(bf16x8*)(xb + i*8) = o;
  }
}

__global__ void cvt_w_kernel(const float* __restrict__ w, bf16* __restrict__ wp){
  int i = blockIdx.x;
  int n = blockIdx.y;
  int ktl = nb_of(i) * FEAT;
  int lo  = lo_of(i) * FEAT;
  long src = (long)(i*FEAT + n) * INSIZE + lo;
  long dst = off_of(i) + (long)n * ktl;
  for (int e = threadIdx.x * 4; e < ktl; e += blockDim.x * 4){
    f32x4 v = __builtin_nontemporal_load((const f32x4*)(w + src + e));
    bf16x4 o;
    o.x = (bf16)v.x; o.y = (bf16)v.y; o.z = (bf16)v.z; o.w = (bf16)v.w;
    *(bf16x4*)(wp + dst + e) = o;
  }
}

// --------- banded GEMM: R5 champion (86.4-88.4 us; session min, 4x measured) --
// BM=512, BN=128, BK=32. 512 threads = 8 waves (4M x 2N), wave tile 128x64.
// 3-stage LDS (120 KiB). Superrow-packed XOR swizzle (bank-conflict = 0,
// measured), pre-permuted global source (linear LDS dest for global_load_lds),
// inline-asm ds_read_b128, free-run single barrier + counted vmcnt(5)/K-tile.
// R16 delta: epilogue stores are NON-TEMPORAL (out is 150 MB write-once —
// keep it from evicting the L3-resident xb; GEMM FETCH was 132 vs 71.5 ideal).
// Plateau documented (R1-R15): 7 alternative structures land 87-160 us;
// binding constraint is 2 waves/SIMD (128-reg acc) -> ds_read latency +
// barrier drain exposed; no pipe >46%. This is the measured minimum.

#define BM 512
#define BN 128
#define BK 32
#define NSTAGE 3
#define A_ELEMS (BM*BK)              // 16384
#define B_ELEMS (BN*BK)              // 4096
#define TILE_ELEMS (A_ELEMS + B_ELEMS)

__device__ __forceinline__ void gload16(const void* g, void* l){
  __builtin_amdgcn_global_load_lds(
      (__attribute__((address_space(1))) unsigned int*)(unsigned long long)g,
      (__attribute__((address_space(3))) unsigned int*)l,
      16, 0, 0);
}

__device__ __forceinline__ unsigned lds_addr(void* p){
  return (unsigned)(unsigned long long)(__attribute__((address_space(3))) void*)p;
}

__device__ __forceinline__ bf16x8 ds_read16(unsigned addr){
  bf16x8 r;
  asm volatile("ds_read_b128 %0, %1" : "=&v"(r) : "v"(addr));
  return r;
}

__global__ __launch_bounds__(512, 2)
void gemm_band_kernel(const bf16* __restrict__ xb, const bf16* __restrict__ wp,
                      const float* __restrict__ bias, float* __restrict__ out){
  __shared__ __align__(16) bf16 lds[NSTAGE * TILE_ELEMS];   // 120 KiB

  const int bid = blockIdx.x;
  const int mt  = bid & 15;            // fast dim: m-tile (L2/L3 locality)
  const int i   = 31 - (bid >> 4);     // slow dim, descending (LPT)
  const int m0  = mt * BM;
  const int nbK = nb_of(i);
  const int ntiles = nbK * (FEAT / BK);    // 4..32
  const int lo  = lo_of(i) * FEAT;
  const int Kt  = nbK * FEAT;
  const long wpo = off_of(i);

  const int tid  = threadIdx.x;
  const int lane = tid & 63;
  const int wid  = tid >> 6;           // 0..7
  const int wr   = wid >> 1;           // 0..3 -> 128-row M strip
  const int wc   = wid & 1;            // 0..1 -> 64-col N strip
  const int fr   = lane & 15;
  const int ks   = lane >> 4;          // 0..3 k-slot (8 bf16)

  const unsigned ldsBase = lds_addr((void*)lds);

  // -------- loop-invariant LDS read BYTE offsets (stage-relative) ----------
  unsigned offA[8], offB[4];
  #pragma unroll
  for (int mi = 0; mi < 8; ++mi){
    const int row = wr*128 + mi*16 + fr;
    const int u = row >> 1;
    const int q = (((row & 1) << 2) | ks) ^ (u & 7);
    offA[mi] = (unsigned)(u*64 + q*8) * 2u;
  }
  #pragma unroll
  for (int ni = 0; ni < 4; ++ni){
    const int row = wc*64 + ni*16 + fr;
    const int u = row >> 1;
    const int q = (((row & 1) << 2) | ks) ^ (u & 7);
    offB[ni] = (unsigned)(A_ELEMS*2) + (unsigned)(u*64 + q*8) * 2u;
  }

  // -------- loop-invariant gload source bases + LDS dest offsets -----------
  const bf16* srcA[4];
  int dstA[4];
  #pragma unroll
  for (int j = 0; j < 4; ++j){
    const int d = wid*256 + j*64 + lane;
    const int u = d >> 3, qq = d & 7;
    const int s8 = qq ^ (u & 7);
    const int r  = 2*u + (s8 >> 2);
    const int sa = s8 & 3;
    srcA[j] = xb + (long)(m0 + r) * INSIZE + lo + sa*8;
    dstA[j] = (wid*256 + j*64) * 8;
  }
  const bf16* srcB;
  {
    const int d = wid*64 + lane;
    const int u = d >> 3, qq = d & 7;
    const int s8 = qq ^ (u & 7);
    const int r  = 2*u + (s8 >> 2);
    const int sb = s8 & 3;
    srcB = wp + wpo + (long)r * Kt + sb*8;
  }
  const int dstB = A_ELEMS + (wid*64) * 8;

  auto issueA = [&](bf16* base, int t, int j){ gload16(srcA[j] + t*BK, base + dstA[j]); };
  auto issueB = [&](bf16* base, int t){ gload16(srcB + t*BK, base + dstB); };

  // -------- prologue: fill stages 0,1 --------------------------------------
  #pragma unroll
  for (int j = 0; j < 4; ++j) issueA(lds, 0, j);
  issueB(lds, 0);
  #pragma unroll
  for (int j = 0; j < 4; ++j) issueA(lds + TILE_ELEMS, 1, j);
  issueB(lds + TILE_ELEMS, 1);

  f32x4 acc[8][4] = {};

  asm volatile("s_waitcnt vmcnt(5)" ::: "memory");   // my stage-0 loads landed
  __builtin_amdgcn_s_barrier();                      // everyone's landed
  asm volatile("" ::: "memory");

  int stC = 0, stPf = 2;
  for (int t = 0; t < ntiles; ++t){
    const unsigned cA = ldsBase + (unsigned)stC * (TILE_ELEMS*2);
    bf16* pfBase = lds + stPf * TILE_ELEMS;
    const bool pf = (t + 2 < ntiles);

    // ---- issue all 12 ds_reads (order: a0-3, b0-3, a4-7 — lgkm in-order)
    bf16x8 a0 = ds_read16(cA + offA[0]);
    bf16x8 a1 = ds_read16(cA + offA[1]);
    bf16x8 a2 = ds_read16(cA + offA[2]);
    bf16x8 a3 = ds_read16(cA + offA[3]);
    bf16x8 b0 = ds_read16(cA + offB[0]);
    bf16x8 b1 = ds_read16(cA + offB[1]);
    bf16x8 b2 = ds_read16(cA + offB[2]);
    bf16x8 b3 = ds_read16(cA + offB[3]);
    bf16x8 a4 = ds_read16(cA + offA[4]);
    bf16x8 a5 = ds_read16(cA + offA[5]);
    bf16x8 a6 = ds_read16(cA + offA[6]);
    bf16x8 a7 = ds_read16(cA + offA[7]);

    // ---- issue next-next tile's staging (writes buf(t-1), safe per barrier)
    if (pf){
      issueA(pfBase, t+2, 0); issueA(pfBase, t+2, 1);
      issueA(pfBase, t+2, 2); issueA(pfBase, t+2, 3);
      issueB(pfBase, t+2);
    }

    // ---- first 8 reads done -> first MFMA cluster
    asm volatile("s_waitcnt lgkmcnt(4)" ::: "memory");
    __builtin_amdgcn_sched_barrier(0);
    __builtin_amdgcn_s_setprio(1);
    acc[0][0] = __builtin_amdgcn_mfma_f32_16x16x32_bf16(a0, b0, acc[0][0], 0,0,0);
    acc[0][1] = __builtin_amdgcn_mfma_f32_16x16x32_bf16(a0, b1, acc[0][1], 0,0,0);
    acc[0][2] = __builtin_amdgcn_mfma_f32_16x16x32_bf16(a0, b2, acc[0][2], 0,0,0);
    acc[0][3] = __builtin_amdgcn_mfma_f32_16x16x32_bf16(a0, b3, acc[0][3], 0,0,0);
    acc[1][0] = __builtin_amdgcn_mfma_f32_16x16x32_bf16(a1, b0, acc[1][0], 0,0,0);
    acc[1][1] = __builtin_amdgcn_mfma_f32_16x16x32_bf16(a1, b1, acc[1][1], 0,0,0);
    acc[1][2] = __builtin_amdgcn_mfma_f32_16x16x32_bf16(a1, b2, acc[1][2], 0,0,0);
    acc[1][3] = __builtin_amdgcn_mfma_f32_16x16x32_bf16(a1, b3, acc[1][3], 0,0,0);
    acc[2][0] = __builtin_amdgcn_mfma_f32_16x16x32_bf16(a2, b0, acc[2][0], 0,0,0);
    acc[2][1] = __builtin_amdgcn_mfma_f32_16x16x32_bf16(a2, b1, acc[2][1], 0,0,0);
    acc[2][2] = __builtin_amdgcn_mfma_f32_16x16x32_bf16(a2, b2, acc[2][2], 0,0,0);
    acc[2][3] = __builtin_amdgcn_mfma_f32_16x16x32_bf16(a2, b3, acc[2][3], 0,0,0);
    acc[3][0] = __builtin_amdgcn_mfma_f32_16x16x32_bf16(a3, b0, acc[3][0], 0,0,0);
    acc[3][1] = __builtin_amdgcn_mfma_f32_16x16x32_bf16(a3, b1, acc[3][1], 0,0,0);
    acc[3][2] = __builtin_amdgcn_mfma_f32_16x16x32_bf16(a3, b2, acc[3][2], 0,0,0);
    acc[3][3] = __builtin_amdgcn_mfma_f32_16x16x32_bf16(a3, b3, acc[3][3], 0,0,0);
    __builtin_amdgcn_s_setprio(0);

    // ---- remaining 4 reads done -> second MFMA cluster
    asm volatile("s_waitcnt lgkmcnt(0)" ::: "memory");
    __builtin_amdgcn_sched_barrier(0);
    __builtin_amdgcn_s_setprio(1);
    acc[4][0] = __builtin_amdgcn_mfma_f32_16x16x32_bf16(a4, b0, acc[4][0], 0,0,0);
    acc[4][1] = __builtin_amdgcn_mfma_f32_16x16x32_bf16(a4, b1, acc[4][1], 0,0,0);
    acc[4][2] = __builtin_amdgcn_mfma_f32_16x16x32_bf16(a4, b2, acc[4][2], 0,0,0);
    acc[4][3] = __builtin_amdgcn_mfma_f32_16x16x32_bf16(a4, b3, acc[4][3], 0,0,0);
    acc[5][0] = __builtin_amdgcn_mfma_f32_16x16x32_bf16(a5, b0, acc[5][0], 0,0,0);
    acc[5][1] = __builtin_amdgcn_mfma_f32_16x16x32_bf16(a5, b1, acc[5][1], 0,0,0);
    acc[5][2] = __builtin_amdgcn_mfma_f32_16x16x32_bf16(a5, b2, acc[5][2], 0,0,0);
    acc[5][3] = __builtin_amdgcn_mfma_f32_16x16x32_bf16(a5, b3, acc[5][3], 0,0,0);
    acc[6][0] = __builtin_amdgcn_mfma_f32_16x16x32_bf16(a6, b0, acc[6][0], 0,0,0);
    acc[6][1] = __builtin_amdgcn_mfma_f32_16x16x32_bf16(a6, b1, acc[6][1], 0,0,0);
    acc[6][2] = __builtin_amdgcn_mfma_f32_16x16x32_bf16(a6, b2, acc[6][2], 0,0,0);
    acc[6][3] = __builtin_amdgcn_mfma_f32_16x16x32_bf16(a6, b3, acc[6][3], 0,0,0);
    acc[7][0] = __builtin_amdgcn_mfma_f32_16x16x32_bf16(a7, b0, acc[7][0], 0,0,0);
    acc[7][1] = __builtin_amdgcn_mfma_f32_16x16x32_bf16(a7, b1, acc[7][1], 0,0,0);
    acc[7][2] = __builtin_amdgcn_mfma_f32_16x16x32_bf16(a7, b2, acc[7][2], 0,0,0);
    acc[7][3] = __builtin_amdgcn_mfma_f32_16x16x32_bf16(a7, b3, acc[7][3], 0,0,0);
    __builtin_amdgcn_s_setprio(0);

    // ---- single per-tile sync: my stage(t+1) retired + everyone ready
    if (t + 1 < ntiles){
      if (pf) asm volatile("s_waitcnt vmcnt(5)" ::: "memory");
      else    asm volatile("s_waitcnt vmcnt(0)" ::: "memory");
      __builtin_amdgcn_s_barrier();
      asm volatile("" ::: "memory");
    }

    stC  = (stC  == NSTAGE-1) ? 0 : stC  + 1;
    stPf = (stPf == NSTAGE-1) ? 0 : stPf + 1;
  }

  // -------- epilogue: C/D layout col = lane&15, row = (lane>>4)*4 + reg ----
  // Non-temporal stores: out is write-once, keep it from evicting xb in L3.
  #pragma unroll
  for (int ni = 0; ni < 4; ++ni){
    const int gcol = i*FEAT + wc*64 + ni*16 + fr;
    const float bv = bias[gcol];
    #pragma unroll
    for (int mi = 0; mi < 8; ++mi){
      const int rbase = m0 + wr*128 + mi*16 + ks*4;
      #pragma unroll
      for (int r2 = 0; r2 < 4; ++r2)
        __builtin_nontemporal_store(acc[mi][ni][r2] + bv,
                                    &out[(long)(rbase + r2) * OUTCOLS + gcol]);
    }
  }
}

// ---------------- fallback (tiny ws): naive fp32, band-limited ----------------
__global__ void naive_kernel(const float* __restrict__ x, const float* __restrict__ w,
                             const float* __restrict__ bias, float* __restrict__ out){
  long idx = (long)blockIdx.x * blockDim.x + threadIdx.x;
  int o = (int)(idx & (OUTCOLS - 1));
  int b = (int)(idx >> 12);
  int i = o >> 7;
  int lo = lo_of(i) * FEAT, hi = (i + 1) * FEAT;
  const float* xr = x + (long)b * INSIZE;
  const float* wr = w + (long)o * INSIZE;
  float s = bias[o];
  for (int k = lo; k < hi; k += 4){
    f32x4 xv = *(const f32x4*)(xr + k);
    f32x4 wv = *(const f32x4*)(wr + k);
    s += xv.x*wv.x + xv.y*wv.y + xv.z*wv.z + xv.w*wv.w;
  }
  out[idx] = s;
}

// ---------------- launch ----------------
extern "C" void kernel_launch(void* const* d_in, const int* in_sizes, int n_in,
                              void* d_out, int out_size, void* d_ws, size_t ws_size,
                              hipStream_t stream) {
  const float* x    = (const float*)d_in[0];
  const float* w    = (const float*)d_in[1];
  const float* bias = (const float*)d_in[2];
  float* out = (float*)d_out;

  const size_t x_bytes = (size_t)BATCH * INSIZE * sizeof(bf16);        // 64 MiB
  const size_t w_bytes = (size_t)228 * FEAT * FEAT * sizeof(bf16);     // ~7.5 MiB
  if (ws_size >= x_bytes + w_bytes){
    bf16* xb = (bf16*)d_ws;
    bf16* wp = (bf16*)((char*)d_ws + x_bytes);
    cvt_x_kernel<<<2048, 256, 0, stream>>>(x, xb, (long)BATCH * INSIZE / 8);
    cvt_w_kernel<<<dim3(NT, FEAT), 256, 0, stream>>>(w, wp);
    gemm_band_kernel<<<dim3(NT * (BATCH/BM)), 512, 0, stream>>>(xb, wp, bias, out);
  } else {
    naive_kernel<<<(long)BATCH * OUTCOLS / 256, 256, 0, stream>>>(x, w, bias, out);
  }
}

// Round 17
// 132.026 us; speedup vs baseline: 1.0138x; 1.0138x over previous
//
#include <hip/hip_runtime.h>
#include <hip/hip_bf16.h>

// Problem constants
#define NT      32      // time steps
#define FEAT    128     // in/out features per step
#define TRIB    8       // band width in blocks
#define BATCH   8192
#define INSIZE  (NT*FEAT)   // 4096
#define OUTCOLS (NT*FEAT)   // 4096

typedef __bf16 bf16;
typedef __bf16 bf16x4 __attribute__((ext_vector_type(4)));
typedef __bf16 bf16x8 __attribute__((ext_vector_type(8)));
typedef float  f32x4  __attribute__((ext_vector_type(4)));

__host__ __device__ __forceinline__ int nb_of(int i){ return i < TRIB ? i + 1 : TRIB; }
__host__ __device__ __forceinline__ int lo_of(int i){ int l = i - TRIB + 1; return l > 0 ? l : 0; }
__host__ __device__ __forceinline__ long off_of(int i){
  long sum = (i <= TRIB) ? (long)i*(i+1)/2 : (long)(TRIB*(TRIB+1)/2) + (long)(i - TRIB)*TRIB;
  return sum * (long)(FEAT*FEAT);
}

// ---------------- conversion kernels (R15 champion config) ----------------
// cvt_x: 32 B loads (2x f32x4) + 16 B stores (bf16x8) — R15-measured best.
// NOTE (R16): non-temporal loads/stores REGRESSED the GEMM (nt stores bypass
// write coalescing; GEMM 87 -> 94-97 us despite FETCH 132 -> 119 MB). Plain
// cached accesses are the measured optimum.

__global__ void cvt_x_kernel(const float* __restrict__ x, bf16* __restrict__ xb, long n8){
  long idx = (long)blockIdx.x * blockDim.x + threadIdx.x;
  long stride = (long)gridDim.x * blockDim.x;
  for (long i = idx; i < n8; i += stride){
    f32x4 v0 = *(const f32x4*)(x + i*8);
    f32x4 v1 = *(const f32x4*)(x + i*8 + 4);
    bf16x8 o;
    o[0]=(bf16)v0.x; o[1]=(bf16)v0.y; o[2]=(bf16)v0.z; o[3]=(bf16)v0.w;
    o[4]=(bf16)v1.x; o[5]=(bf16)v1.y; o[6]=(bf16)v1.z; o[7]=(bf16)v1.w;
    *(bf16x8*)(xb + i*8) = o;
  }
}

__global__ void cvt_w_kernel(const float* __restrict__ w, bf16* __restrict__ wp){
  int i = blockIdx.x;
  int n = blockIdx.y;
  int ktl = nb_of(i) * FEAT;
  int lo  = lo_of(i) * FEAT;
  long src = (long)(i*FEAT + n) * INSIZE + lo;
  long dst = off_of(i) + (long)n * ktl;
  for (int e = threadIdx.x * 4; e < ktl; e += blockDim.x * 4){
    f32x4 v = *(const f32x4*)(w + src + e);
    bf16x4 o;
    o.x = (bf16)v.x; o.y = (bf16)v.y; o.z = (bf16)v.z; o.w = (bf16)v.w;
    *(bf16x4*)(wp + dst + e) = o;
  }
}

// --------- banded GEMM: R5 champion (86.4-88.4 us; session min, 4x measured) --
// BM=512, BN=128, BK=32. 512 threads = 8 waves (4M x 2N), wave tile 128x64.
// 3-stage LDS (120 KiB). Superrow-packed XOR swizzle (bank-conflict = 0,
// measured), pre-permuted global source (linear LDS dest for global_load_lds),
// inline-asm ds_read_b128, free-run single barrier + counted vmcnt(5)/K-tile.
// Session ledger (R1-R16): 8 GEMM structures (2/4-phase, free-run, 2-blk/CU
// x2, 32x32 MFMA, A-from-L2, fused-cvt x3) land 87-160 us; nt-store regresses;
// binding constraint is 2 waves/SIMD (128-reg acc) -> ds_read latency +
// barrier drain exposed; no pipe >46%. This is the measured minimum.

#define BM 512
#define BN 128
#define BK 32
#define NSTAGE 3
#define A_ELEMS (BM*BK)              // 16384
#define B_ELEMS (BN*BK)              // 4096
#define TILE_ELEMS (A_ELEMS + B_ELEMS)

__device__ __forceinline__ void gload16(const void* g, void* l){
  __builtin_amdgcn_global_load_lds(
      (__attribute__((address_space(1))) unsigned int*)(unsigned long long)g,
      (__attribute__((address_space(3))) unsigned int*)l,
      16, 0, 0);
}

__device__ __forceinline__ unsigned lds_addr(void* p){
  return (unsigned)(unsigned long long)(__attribute__((address_space(3))) void*)p;
}

__device__ __forceinline__ bf16x8 ds_read16(unsigned addr){
  bf16x8 r;
  asm volatile("ds_read_b128 %0, %1" : "=&v"(r) : "v"(addr));
  return r;
}

__global__ __launch_bounds__(512, 2)
void gemm_band_kernel(const bf16* __restrict__ xb, const bf16* __restrict__ wp,
                      const float* __restrict__ bias, float* __restrict__ out){
  __shared__ __align__(16) bf16 lds[NSTAGE * TILE_ELEMS];   // 120 KiB

  const int bid = blockIdx.x;
  const int mt  = bid & 15;            // fast dim: m-tile (L2/L3 locality)
  const int i   = 31 - (bid >> 4);     // slow dim, descending (LPT)
  const int m0  = mt * BM;
  const int nbK = nb_of(i);
  const int ntiles = nbK * (FEAT / BK);    // 4..32
  const int lo  = lo_of(i) * FEAT;
  const int Kt  = nbK * FEAT;
  const long wpo = off_of(i);

  const int tid  = threadIdx.x;
  const int lane = tid & 63;
  const int wid  = tid >> 6;           // 0..7
  const int wr   = wid >> 1;           // 0..3 -> 128-row M strip
  const int wc   = wid & 1;            // 0..1 -> 64-col N strip
  const int fr   = lane & 15;
  const int ks   = lane >> 4;          // 0..3 k-slot (8 bf16)

  const unsigned ldsBase = lds_addr((void*)lds);

  // -------- loop-invariant LDS read BYTE offsets (stage-relative) ----------
  unsigned offA[8], offB[4];
  #pragma unroll
  for (int mi = 0; mi < 8; ++mi){
    const int row = wr*128 + mi*16 + fr;
    const int u = row >> 1;
    const int q = (((row & 1) << 2) | ks) ^ (u & 7);
    offA[mi] = (unsigned)(u*64 + q*8) * 2u;
  }
  #pragma unroll
  for (int ni = 0; ni < 4; ++ni){
    const int row = wc*64 + ni*16 + fr;
    const int u = row >> 1;
    const int q = (((row & 1) << 2) | ks) ^ (u & 7);
    offB[ni] = (unsigned)(A_ELEMS*2) + (unsigned)(u*64 + q*8) * 2u;
  }

  // -------- loop-invariant gload source bases + LDS dest offsets -----------
  const bf16* srcA[4];
  int dstA[4];
  #pragma unroll
  for (int j = 0; j < 4; ++j){
    const int d = wid*256 + j*64 + lane;
    const int u = d >> 3, qq = d & 7;
    const int s8 = qq ^ (u & 7);
    const int r  = 2*u + (s8 >> 2);
    const int sa = s8 & 3;
    srcA[j] = xb + (long)(m0 + r) * INSIZE + lo + sa*8;
    dstA[j] = (wid*256 + j*64) * 8;
  }
  const bf16* srcB;
  {
    const int d = wid*64 + lane;
    const int u = d >> 3, qq = d & 7;
    const int s8 = qq ^ (u & 7);
    const int r  = 2*u + (s8 >> 2);
    const int sb = s8 & 3;
    srcB = wp + wpo + (long)r * Kt + sb*8;
  }
  const int dstB = A_ELEMS + (wid*64) * 8;

  auto issueA = [&](bf16* base, int t, int j){ gload16(srcA[j] + t*BK, base + dstA[j]); };
  auto issueB = [&](bf16* base, int t){ gload16(srcB + t*BK, base + dstB); };

  // -------- prologue: fill stages 0,1 --------------------------------------
  #pragma unroll
  for (int j = 0; j < 4; ++j) issueA(lds, 0, j);
  issueB(lds, 0);
  #pragma unroll
  for (int j = 0; j < 4; ++j) issueA(lds + TILE_ELEMS, 1, j);
  issueB(lds + TILE_ELEMS, 1);

  f32x4 acc[8][4] = {};

  asm volatile("s_waitcnt vmcnt(5)" ::: "memory");   // my stage-0 loads landed
  __builtin_amdgcn_s_barrier();                      // everyone's landed
  asm volatile("" ::: "memory");

  int stC = 0, stPf = 2;
  for (int t = 0; t < ntiles; ++t){
    const unsigned cA = ldsBase + (unsigned)stC * (TILE_ELEMS*2);
    bf16* pfBase = lds + stPf * TILE_ELEMS;
    const bool pf = (t + 2 < ntiles);

    // ---- issue all 12 ds_reads (order: a0-3, b0-3, a4-7 — lgkm in-order)
    bf16x8 a0 = ds_read16(cA + offA[0]);
    bf16x8 a1 = ds_read16(cA + offA[1]);
    bf16x8 a2 = ds_read16(cA + offA[2]);
    bf16x8 a3 = ds_read16(cA + offA[3]);
    bf16x8 b0 = ds_read16(cA + offB[0]);
    bf16x8 b1 = ds_read16(cA + offB[1]);
    bf16x8 b2 = ds_read16(cA + offB[2]);
    bf16x8 b3 = ds_read16(cA + offB[3]);
    bf16x8 a4 = ds_read16(cA + offA[4]);
    bf16x8 a5 = ds_read16(cA + offA[5]);
    bf16x8 a6 = ds_read16(cA + offA[6]);
    bf16x8 a7 = ds_read16(cA + offA[7]);

    // ---- issue next-next tile's staging (writes buf(t-1), safe per barrier)
    if (pf){
      issueA(pfBase, t+2, 0); issueA(pfBase, t+2, 1);
      issueA(pfBase, t+2, 2); issueA(pfBase, t+2, 3);
      issueB(pfBase, t+2);
    }

    // ---- first 8 reads done -> first MFMA cluster
    asm volatile("s_waitcnt lgkmcnt(4)" ::: "memory");
    __builtin_amdgcn_sched_barrier(0);
    __builtin_amdgcn_s_setprio(1);
    acc[0][0] = __builtin_amdgcn_mfma_f32_16x16x32_bf16(a0, b0, acc[0][0], 0,0,0);
    acc[0][1] = __builtin_amdgcn_mfma_f32_16x16x32_bf16(a0, b1, acc[0][1], 0,0,0);
    acc[0][2] = __builtin_amdgcn_mfma_f32_16x16x32_bf16(a0, b2, acc[0][2], 0,0,0);
    acc[0][3] = __builtin_amdgcn_mfma_f32_16x16x32_bf16(a0, b3, acc[0][3], 0,0,0);
    acc[1][0] = __builtin_amdgcn_mfma_f32_16x16x32_bf16(a1, b0, acc[1][0], 0,0,0);
    acc[1][1] = __builtin_amdgcn_mfma_f32_16x16x32_bf16(a1, b1, acc[1][1], 0,0,0);
    acc[1][2] = __builtin_amdgcn_mfma_f32_16x16x32_bf16(a1, b2, acc[1][2], 0,0,0);
    acc[1][3] = __builtin_amdgcn_mfma_f32_16x16x32_bf16(a1, b3, acc[1][3], 0,0,0);
    acc[2][0] = __builtin_amdgcn_mfma_f32_16x16x32_bf16(a2, b0, acc[2][0], 0,0,0);
    acc[2][1] = __builtin_amdgcn_mfma_f32_16x16x32_bf16(a2, b1, acc[2][1], 0,0,0);
    acc[2][2] = __builtin_amdgcn_mfma_f32_16x16x32_bf16(a2, b2, acc[2][2], 0,0,0);
    acc[2][3] = __builtin_amdgcn_mfma_f32_16x16x32_bf16(a2, b3, acc[2][3], 0,0,0);
    acc[3][0] = __builtin_amdgcn_mfma_f32_16x16x32_bf16(a3, b0, acc[3][0], 0,0,0);
    acc[3][1] = __builtin_amdgcn_mfma_f32_16x16x32_bf16(a3, b1, acc[3][1], 0,0,0);
    acc[3][2] = __builtin_amdgcn_mfma_f32_16x16x32_bf16(a3, b2, acc[3][2], 0,0,0);
    acc[3][3] = __builtin_amdgcn_mfma_f32_16x16x32_bf16(a3, b3, acc[3][3], 0,0,0);
    __builtin_amdgcn_s_setprio(0);

    // ---- remaining 4 reads done -> second MFMA cluster
    asm volatile("s_waitcnt lgkmcnt(0)" ::: "memory");
    __builtin_amdgcn_sched_barrier(0);
    __builtin_amdgcn_s_setprio(1);
    acc[4][0] = __builtin_amdgcn_mfma_f32_16x16x32_bf16(a4, b0, acc[4][0], 0,0,0);
    acc[4][1] = __builtin_amdgcn_mfma_f32_16x16x32_bf16(a4, b1, acc[4][1], 0,0,0);
    acc[4][2] = __builtin_amdgcn_mfma_f32_16x16x32_bf16(a4, b2, acc[4][2], 0,0,0);
    acc[4][3] = __builtin_amdgcn_mfma_f32_16x16x32_bf16(a4, b3, acc[4][3], 0,0,0);
    acc[5][0] = __builtin_amdgcn_mfma_f32_16x16x32_bf16(a5, b0, acc[5][0], 0,0,0);
    acc[5][1] = __builtin_amdgcn_mfma_f32_16x16x32_bf16(a5, b1, acc[5][1], 0,0,0);
    acc[5][2] = __builtin_amdgcn_mfma_f32_16x16x32_bf16(a5, b2, acc[5][2], 0,0,0);
    acc[5][3] = __builtin_amdgcn_mfma_f32_16x16x32_bf16(a5, b3, acc[5][3], 0,0,0);
    acc[6][0] = __builtin_amdgcn_mfma_f32_16x16x32_bf16(a6, b0, acc[6][0], 0,0,0);
    acc[6][1] = __builtin_amdgcn_mfma_f32_16x16x32_bf16(a6, b1, acc[6][1], 0,0,0);
    acc[6][2] = __builtin_amdgcn_mfma_f32_16x16x32_bf16(a6, b2, acc[6][2], 0,0,0);
    acc[6][3] = __builtin_amdgcn_mfma_f32_16x16x32_bf16(a6, b3, acc[6][3], 0,0,0);
    acc[7][0] = __builtin_amdgcn_mfma_f32_16x16x32_bf16(a7, b0, acc[7][0], 0,0,0);
    acc[7][1] = __builtin_amdgcn_mfma_f32_16x16x32_bf16(a7, b1, acc[7][1], 0,0,0);
    acc[7][2] = __builtin_amdgcn_mfma_f32_16x16x32_bf16(a7, b2, acc[7][2], 0,0,0);
    acc[7][3] = __builtin_amdgcn_mfma_f32_16x16x32_bf16(a7, b3, acc[7][3], 0,0,0);
    __builtin_amdgcn_s_setprio(0);

    // ---- single per-tile sync: my stage(t+1) retired + everyone ready
    if (t + 1 < ntiles){
      if (pf) asm volatile("s_waitcnt vmcnt(5)" ::: "memory");
      else    asm volatile("s_waitcnt vmcnt(0)" ::: "memory");
      __builtin_amdgcn_s_barrier();
      asm volatile("" ::: "memory");
    }

    stC  = (stC  == NSTAGE-1) ? 0 : stC  + 1;
    stPf = (stPf == NSTAGE-1) ? 0 : stPf + 1;
  }

  // -------- epilogue: C/D layout col = lane&15, row = (lane>>4)*4 + reg ----
  #pragma unroll
  for (int ni = 0; ni < 4; ++ni){
    const int gcol = i*FEAT + wc*64 + ni*16 + fr;
    const float bv = bias[gcol];
    #pragma unroll
    for (int mi = 0; mi < 8; ++mi){
      const int rbase = m0 + wr*128 + mi*16 + ks*4;
      #pragma unroll
      for (int r2 = 0; r2 < 4; ++r2)
        out[(long)(rbase + r2) * OUTCOLS + gcol] = acc[mi][ni][r2] + bv;
    }
  }
}

// ---------------- fallback (tiny ws): naive fp32, band-limited ----------------
__global__ void naive_kernel(const float* __restrict__ x, const float* __restrict__ w,
                             const float* __restrict__ bias, float* __restrict__ out){
  long idx = (long)blockIdx.x * blockDim.x + threadIdx.x;
  int o = (int)(idx & (OUTCOLS - 1));
  int b = (int)(idx >> 12);
  int i = o >> 7;
  int lo = lo_of(i) * FEAT, hi = (i + 1) * FEAT;
  const float* xr = x + (long)b * INSIZE;
  const float* wr = w + (long)o * INSIZE;
  float s = bias[o];
  for (int k = lo; k < hi; k += 4){
    f32x4 xv = *(const f32x4*)(xr + k);
    f32x4 wv = *(const f32x4*)(wr + k);
    s += xv.x*wv.x + xv.y*wv.y + xv.z*wv.z + xv.w*wv.w;
  }
  out[idx] = s;
}

// ---------------- launch ----------------
extern "C" void kernel_launch(void* const* d_in, const int* in_sizes, int n_in,
                              void* d_out, int out_size, void* d_ws, size_t ws_size,
                              hipStream_t stream) {
  const float* x    = (const float*)d_in[0];
  const float* w    = (const float*)d_in[1];
  const float* bias = (const float*)d_in[2];
  float* out = (float*)d_out;

  const size_t x_bytes = (size_t)BATCH * INSIZE * sizeof(bf16);        // 64 MiB
  const size_t w_bytes = (size_t)228 * FEAT * FEAT * sizeof(bf16);     // ~7.5 MiB
  if (ws_size >= x_bytes + w_bytes){
    bf16* xb = (bf16*)d_ws;
    bf16* wp = (bf16*)((char*)d_ws + x_bytes);
    cvt_x_kernel<<<2048, 256, 0, stream>>>(x, xb, (long)BATCH * INSIZE / 8);
    cvt_w_kernel<<<dim3(NT, FEAT), 256, 0, stream>>>(w, wp);
    gemm_band_kernel<<<dim3(NT * (BATCH/BM)), 512, 0, stream>>>(xb, wp, bias, out);
  } else {
    naive_kernel<<<(long)BATCH * OUTCOLS / 256, 256, 0, stream>>>(x, w, bias, out);
  }
}